// Round 1
// baseline (231.033 us; speedup 1.0000x reference)
//
#include <hip/hip_runtime.h>

// One 64-lane wave per (b,c) slice of 32x32 fp32.
// Block = 256 threads = 4 independent waves; no LDS, no block sync.
// Lane i loads float4s at positions {i, i+64, i+128, i+192} (coalesced 16B/lane),
// wave-reduces argmax (first-occurrence tiebreak), applies drop-block mask, stores.
__global__ __launch_bounds__(256) void drop_block_kernel(
    const float* __restrict__ x,
    const int* __restrict__ T,
    const int* __restrict__ dropb,
    float* __restrict__ out,
    int n_slices) {
  const int wave_in_blk = threadIdx.x >> 6;
  const int lane = threadIdx.x & 63;
  const int slice = blockIdx.x * 4 + wave_in_blk;
  if (slice >= n_slices) return;

  const float4* __restrict__ x4 = (const float4*)x + (size_t)slice * 256;
  float4* __restrict__ o4 = (float4*)out + (size_t)slice * 256;

  // 16 floats per lane, held in registers the whole time (single pass).
  float4 v0 = x4[lane];
  float4 v1 = x4[lane + 64];
  float4 v2 = x4[lane + 128];
  float4 v3 = x4[lane + 192];

  const int sel = T[slice];

  if (!sel) {
    // wave-uniform passthrough
    o4[lane] = v0;
    o4[lane + 64] = v1;
    o4[lane + 128] = v2;
    o4[lane + 192] = v3;
    return;
  }

  // ---- in-lane argmax, ascending index order, strict '>' => first occurrence wins
  float bv = v0.x;
  int bi = lane * 4;
#define CHK(val, idx)                  \
  do {                                 \
    float _v = (val);                  \
    if (_v > bv) { bv = _v; bi = (idx); } \
  } while (0)
  CHK(v0.y, lane * 4 + 1);
  CHK(v0.z, lane * 4 + 2);
  CHK(v0.w, lane * 4 + 3);
  int b1 = (lane + 64) * 4;
  CHK(v1.x, b1); CHK(v1.y, b1 + 1); CHK(v1.z, b1 + 2); CHK(v1.w, b1 + 3);
  int b2 = (lane + 128) * 4;
  CHK(v2.x, b2); CHK(v2.y, b2 + 1); CHK(v2.z, b2 + 2); CHK(v2.w, b2 + 3);
  int b3 = (lane + 192) * 4;
  CHK(v3.x, b3); CHK(v3.y, b3 + 1); CHK(v3.z, b3 + 2); CHK(v3.w, b3 + 3);
#undef CHK

  // ---- cross-lane butterfly reduce (64-wide), lowest-index tiebreak
  for (int off = 32; off > 0; off >>= 1) {
    float ov = __shfl_xor(bv, off, 64);
    int oi = __shfl_xor(bi, off, 64);
    if (ov > bv || (ov == bv && oi < bi)) { bv = ov; bi = oi; }
  }

  // ---- box + normalization (exact: sum(S) is an integer)
  const int half = dropb[0] >> 1;  // floor(drop_block/2)
  const int mh = bi >> 5;
  const int mw = bi & 31;
  int h1 = mh - half; h1 = h1 < 0 ? 0 : (h1 > 31 ? 31 : h1);
  int h2 = mh + half; h2 = h2 < 0 ? 0 : (h2 > 31 ? 31 : h2);
  int w1 = mw - half; w1 = w1 < 0 ? 0 : (w1 > 31 ? 31 : w1);
  int w2 = mw + half; w2 = w2 < 0 ? 0 : (w2 > 31 ? 31 : w2);
  const int area = (h2 - h1 + 1) * (w2 - w1 + 1);
  const float lam = 1024.0f / (float)(1024 - area);

  // ---- apply mask + scale, store
#define APPLY(vec, base)                                              \
  do {                                                                \
    float4 _r;                                                        \
    {                                                                 \
      int _i = (base);                                                \
      int _r0 = _i >> 5, _c0 = _i & 31;                               \
      bool _in = (_r0 >= h1) & (_r0 <= h2) & (_c0 >= w1) & (_c0 <= w2); \
      _r.x = _in ? 0.0f : vec.x * lam;                                \
      _c0 = (_i + 1) & 31; _r0 = (_i + 1) >> 5;                       \
      _in = (_r0 >= h1) & (_r0 <= h2) & (_c0 >= w1) & (_c0 <= w2);    \
      _r.y = _in ? 0.0f : vec.y * lam;                                \
      _c0 = (_i + 2) & 31; _r0 = (_i + 2) >> 5;                       \
      _in = (_r0 >= h1) & (_r0 <= h2) & (_c0 >= w1) & (_c0 <= w2);    \
      _r.z = _in ? 0.0f : vec.z * lam;                                \
      _c0 = (_i + 3) & 31; _r0 = (_i + 3) >> 5;                       \
      _in = (_r0 >= h1) & (_r0 <= h2) & (_c0 >= w1) & (_c0 <= w2);    \
      _r.w = _in ? 0.0f : vec.w * lam;                                \
    }                                                                 \
    o4[(base) >> 2] = _r;                                             \
  } while (0)

  APPLY(v0, lane * 4);
  APPLY(v1, (lane + 64) * 4);
  APPLY(v2, (lane + 128) * 4);
  APPLY(v3, (lane + 192) * 4);
#undef APPLY
}

extern "C" void kernel_launch(void* const* d_in, const int* in_sizes, int n_in,
                              void* d_out, int out_size, void* d_ws, size_t ws_size,
                              hipStream_t stream) {
  const float* x = (const float*)d_in[0];
  const int* T = (const int*)d_in[1];
  const int* dropb = (const int*)d_in[2];
  float* out = (float*)d_out;

  const int n_slices = in_sizes[1];  // 128*256 = 32768
  const int blocks = (n_slices + 3) / 4;
  drop_block_kernel<<<blocks, 256, 0, stream>>>(x, T, dropb, out, n_slices);
}

// Round 3
// 220.843 us; speedup vs baseline: 1.0461x; 1.0461x over previous
//
#include <hip/hip_runtime.h>

// Native 4-float vector (clang ext_vector_type) — required for
// __builtin_nontemporal_load/store (HIP's float4 class is rejected).
typedef float nfloat4 __attribute__((ext_vector_type(4)));

// One 64-lane wave per (b,c) slice of 32x32 fp32.
// Block = 256 threads = 4 independent waves; no LDS, no block sync.
// Lane i loads float4s at positions {i, i+64, i+128, i+192} (coalesced 16B/lane),
// wave-reduces argmax (first-occurrence tiebreak), applies drop-block mask, stores.
// All global traffic is nontemporal (pure stream, zero reuse).
__global__ __launch_bounds__(256) void drop_block_kernel(
    const float* __restrict__ x,
    const int* __restrict__ T,
    const int* __restrict__ dropb,
    float* __restrict__ out,
    int n_slices) {
  const int wave_in_blk = threadIdx.x >> 6;
  const int lane = threadIdx.x & 63;
  const int slice = blockIdx.x * 4 + wave_in_blk;
  if (slice >= n_slices) return;

  const nfloat4* __restrict__ x4 = (const nfloat4*)x + (size_t)slice * 256;
  nfloat4* __restrict__ o4 = (nfloat4*)out + (size_t)slice * 256;

  // 16 floats per lane, held in registers the whole time (single pass).
  nfloat4 v0 = __builtin_nontemporal_load(&x4[lane]);
  nfloat4 v1 = __builtin_nontemporal_load(&x4[lane + 64]);
  nfloat4 v2 = __builtin_nontemporal_load(&x4[lane + 128]);
  nfloat4 v3 = __builtin_nontemporal_load(&x4[lane + 192]);

  const int sel = T[slice];

  if (!sel) {
    // wave-uniform passthrough
    __builtin_nontemporal_store(v0, &o4[lane]);
    __builtin_nontemporal_store(v1, &o4[lane + 64]);
    __builtin_nontemporal_store(v2, &o4[lane + 128]);
    __builtin_nontemporal_store(v3, &o4[lane + 192]);
    return;
  }

  // ---- in-lane argmax: 4 independent chunk chains (ILP), then ordered merge.
  // Strict '>' with ascending-index evaluation => first occurrence wins.
#define ARG4(vec, base, BV, BI)                         \
  float BV = vec.x; int BI = (base);                    \
  if (vec.y > BV) { BV = vec.y; BI = (base) + 1; }      \
  if (vec.z > BV) { BV = vec.z; BI = (base) + 2; }      \
  if (vec.w > BV) { BV = vec.w; BI = (base) + 3; }

  ARG4(v0, lane * 4, bv0, bi0)
  ARG4(v1, (lane + 64) * 4, bv1, bi1)
  ARG4(v2, (lane + 128) * 4, bv2, bi2)
  ARG4(v3, (lane + 192) * 4, bv3, bi3)
#undef ARG4

  // ordered merge (chunk 0 has the lowest indices, keep strict '>')
  float bv = bv0; int bi = bi0;
  if (bv1 > bv) { bv = bv1; bi = bi1; }
  if (bv2 > bv) { bv = bv2; bi = bi2; }
  if (bv3 > bv) { bv = bv3; bi = bi3; }

  // ---- cross-lane butterfly reduce (64-wide), lowest-index tiebreak
  for (int off = 32; off > 0; off >>= 1) {
    float ov = __shfl_xor(bv, off, 64);
    int oi = __shfl_xor(bi, off, 64);
    if (ov > bv || (ov == bv && oi < bi)) { bv = ov; bi = oi; }
  }

  // ---- box + normalization (exact: sum(S) is an integer)
  const int half = dropb[0] >> 1;  // floor(drop_block/2)
  const int mh = bi >> 5;
  const int mw = bi & 31;
  int h1 = mh - half; h1 = h1 < 0 ? 0 : (h1 > 31 ? 31 : h1);
  int h2 = mh + half; h2 = h2 < 0 ? 0 : (h2 > 31 ? 31 : h2);
  int w1 = mw - half; w1 = w1 < 0 ? 0 : (w1 > 31 ? 31 : w1);
  int w2 = mw + half; w2 = w2 < 0 ? 0 : (w2 > 31 ? 31 : w2);
  const int area = (h2 - h1 + 1) * (w2 - w1 + 1);
  const float lam = 1024.0f / (float)(1024 - area);

  // ---- apply mask + scale, store (nontemporal)
#define APPLY(vec, base)                                              \
  do {                                                                \
    nfloat4 _r;                                                       \
    {                                                                 \
      int _i = (base);                                                \
      int _r0 = _i >> 5, _c0 = _i & 31;                               \
      bool _in = (_r0 >= h1) & (_r0 <= h2) & (_c0 >= w1) & (_c0 <= w2); \
      _r.x = _in ? 0.0f : vec.x * lam;                                \
      _c0 = (_i + 1) & 31; _r0 = (_i + 1) >> 5;                       \
      _in = (_r0 >= h1) & (_r0 <= h2) & (_c0 >= w1) & (_c0 <= w2);    \
      _r.y = _in ? 0.0f : vec.y * lam;                                \
      _c0 = (_i + 2) & 31; _r0 = (_i + 2) >> 5;                       \
      _in = (_r0 >= h1) & (_r0 <= h2) & (_c0 >= w1) & (_c0 <= w2);    \
      _r.z = _in ? 0.0f : vec.z * lam;                                \
      _c0 = (_i + 3) & 31; _r0 = (_i + 3) >> 5;                       \
      _in = (_r0 >= h1) & (_r0 <= h2) & (_c0 >= w1) & (_c0 <= w2);    \
      _r.w = _in ? 0.0f : vec.w * lam;                                \
    }                                                                 \
    __builtin_nontemporal_store(_r, &o4[(base) >> 2]);                \
  } while (0)

  APPLY(v0, lane * 4);
  APPLY(v1, (lane + 64) * 4);
  APPLY(v2, (lane + 128) * 4);
  APPLY(v3, (lane + 192) * 4);
#undef APPLY
}

extern "C" void kernel_launch(void* const* d_in, const int* in_sizes, int n_in,
                              void* d_out, int out_size, void* d_ws, size_t ws_size,
                              hipStream_t stream) {
  const float* x = (const float*)d_in[0];
  const int* T = (const int*)d_in[1];
  const int* dropb = (const int*)d_in[2];
  float* out = (float*)d_out;

  const int n_slices = in_sizes[1];  // 128*256 = 32768
  const int blocks = (n_slices + 3) / 4;
  drop_block_kernel<<<blocks, 256, 0, stream>>>(x, T, dropb, out, n_slices);
}